// Round 3
// baseline (160.091 us; speedup 1.0000x reference)
//
#include <hip/hip_runtime.h>
#include <hip/hip_bf16.h>

// SelfAttentionLayer: B=64, N=1024, C=128, D=64
// R2: attn with ZERO LDS staging / ZERO barriers — K and V^T fragments load
// 16B-contiguous per lane straight from global (L1/L2-hot, XCD-swizzled);
// only the per-wave P C-layout->A-layout round-trip stays in LDS. 32 q/wave.
// Register prefetch of next K-tile under PV. qkv: qf stream dropped (q
// reconstructed from bf16 scaled copy), 128-row blocks amortize weight
// gathers, vt stores packed b128 via v_perm.

#define Bsz 64
#define Nsz 1024
#define Csz 128
#define Dsz 64

typedef __attribute__((ext_vector_type(8))) short short8;
typedef __attribute__((ext_vector_type(4))) float f32x4;

__device__ __forceinline__ unsigned short f2bf(float f) {
    union { float f; unsigned u; } v; v.f = f;
    unsigned r = v.u + 0x7FFF + ((v.u >> 16) & 1);
    return (unsigned short)(r >> 16);
}
__device__ __forceinline__ float bf2f(unsigned short h) {
    union { unsigned u; float f; } v; v.u = ((unsigned)h) << 16;
    return v.f;
}
// pack two fp32 -> bf16x2 dword, round-nearest (ties-up), 3 VALU ops total
__device__ __forceinline__ unsigned pack_bf16rn(float lo, float hi) {
    unsigned ulo = __float_as_uint(lo) + 0x8000u;
    unsigned uhi = __float_as_uint(hi) + 0x8000u;
    return __builtin_amdgcn_perm(uhi, ulo, 0x07060302u);
}

#define SCq (0.125f * 1.44269504f)     // 1/sqrt(D) * log2(e), folded into qs
#define INV_SC (1.0f / (0.125f * 1.44269504f))

// ---------------- Kernel A: QKV projection via MFMA ----------------
// grid 512 blocks x 256 thr; block = 128 rows (2 chunks of 64); wave = d-tile.
__global__ __launch_bounds__(256, 2) void qkv_kernel(
    const float* __restrict__ x,
    const float* __restrict__ Wq, const float* __restrict__ bq,
    const float* __restrict__ Wk, const float* __restrict__ bk,
    const float* __restrict__ Wv, const float* __restrict__ bv,
    unsigned short* __restrict__ qs, unsigned short* __restrict__ ksc,
    unsigned short* __restrict__ vt)
{
    __shared__ short xh[8192];   // [4 rt][4 ks][64 lane][8] A-frag layout
    __shared__ short xl[8192];
    const int t    = threadIdx.x;
    const int lane = t & 63;
    const int l16  = lane & 15, quad = lane >> 4;
    const int dt   = t >> 6;
    const long rowbase = (long)blockIdx.x * 128;
    const int d = dt * 16 + l16;

    // ---- weight B-frags in registers, loaded ONCE per block ----
    short8 wqh[4], wql[4], wkf[4], wvf[4];
    #pragma unroll
    for (int ksi = 0; ksi < 4; ksi++) {
        #pragma unroll
        for (int j = 0; j < 8; j++) {
            int c = ksi * 32 + quad * 8 + j;
            float w = Wq[c * Dsz + d];
            unsigned short h = f2bf(w);
            wqh[ksi][j] = (short)h;
            wql[ksi][j] = (short)f2bf(w - bf2f(h));
            wkf[ksi][j] = (short)f2bf(Wk[c * Dsz + d]);
            wvf[ksi][j] = (short)f2bf(Wv[c * Dsz + d]);
        }
    }
    const float bqd = bq[d], bkd = bk[d], bvd = bv[d];
    const long b = rowbase >> 10;

    for (int chunk = 0; chunk < 2; chunk++) {
        const long rowc = rowbase + chunk * 64;
        if (chunk) __syncthreads();          // xh/xl reuse fence

        // ---- stage x chunk -> bf16 hi/lo in A-frag layout ----
        {
            const int row = t & 63;
            const float* xrow = x + (rowc + row) * Csz;
            #pragma unroll
            for (int p = 0; p < 4; p++) {
                int cb = (t >> 6) + p * 4;
                float4 a = *(const float4*)(xrow + cb * 8);
                float4 bb = *(const float4*)(xrow + cb * 8 + 4);
                float f[8] = {a.x, a.y, a.z, a.w, bb.x, bb.y, bb.z, bb.w};
                short8 hi, lo;
                #pragma unroll
                for (int i = 0; i < 8; i++) {
                    unsigned short h = f2bf(f[i]);
                    hi[i] = (short)h;
                    lo[i] = (short)f2bf(f[i] - bf2f(h));
                }
                int unit = ((row >> 4) * 4 + (cb >> 2)) * 64 + ((row & 15) | ((cb & 3) << 4));
                *(short8*)&xh[unit * 8] = hi;
                *(short8*)&xl[unit * 8] = lo;
            }
        }
        __syncthreads();

        f32x4 aq[4], ak[4], av[4];
        #pragma unroll
        for (int i = 0; i < 4; i++) {
            aq[i] = (f32x4){0.f, 0.f, 0.f, 0.f};
            ak[i] = (f32x4){0.f, 0.f, 0.f, 0.f};
            av[i] = (f32x4){0.f, 0.f, 0.f, 0.f};
        }
        #pragma unroll
        for (int ksi = 0; ksi < 4; ksi++) {
            #pragma unroll
            for (int rt = 0; rt < 4; rt++) {
                short8 ah = *(const short8*)&xh[((rt * 4 + ksi) * 64 + lane) * 8];
                short8 al = *(const short8*)&xl[((rt * 4 + ksi) * 64 + lane) * 8];
                aq[rt] = __builtin_amdgcn_mfma_f32_16x16x32_bf16(ah, wqh[ksi], aq[rt], 0, 0, 0);
                aq[rt] = __builtin_amdgcn_mfma_f32_16x16x32_bf16(al, wqh[ksi], aq[rt], 0, 0, 0);
                aq[rt] = __builtin_amdgcn_mfma_f32_16x16x32_bf16(ah, wql[ksi], aq[rt], 0, 0, 0);
                ak[rt] = __builtin_amdgcn_mfma_f32_16x16x32_bf16(ah, wkf[ksi], ak[rt], 0, 0, 0);
                av[rt] = __builtin_amdgcn_mfma_f32_16x16x32_bf16(ah, wvf[ksi], av[rt], 0, 0, 0);
            }
        }

        // ---- epilogue: bias+relu; qs/ksc scalar b16, vt packed b128 ----
        float vv[16];
        #pragma unroll
        for (int rt = 0; rt < 4; rt++) {
            #pragma unroll
            for (int r = 0; r < 4; r++) {
                long n = rowc + rt * 16 + quad * 4 + r;
                float q = fmaxf(aq[rt][r] + bqd, 0.f);
                float k = fmaxf(ak[rt][r] + bkd, 0.f);
                float v = fmaxf(av[rt][r] + bvd, 0.f);
                qs[n * Dsz + d]  = f2bf(q * SCq);
                ksc[n * Dsz + d] = f2bf(k);
                vv[r * 4 + rt] = v;   // pi(n&63) = (n&15)*4 + (n>>4); local ofs r*4+rt
            }
        }
        unsigned short* vp = vt + b * (Dsz * Nsz) + (long)d * Nsz + (rowc & 1023) + quad * 16;
        uint4 p0 = make_uint4(pack_bf16rn(vv[0], vv[1]),  pack_bf16rn(vv[2], vv[3]),
                              pack_bf16rn(vv[4], vv[5]),  pack_bf16rn(vv[6], vv[7]));
        uint4 p1 = make_uint4(pack_bf16rn(vv[8], vv[9]),  pack_bf16rn(vv[10], vv[11]),
                              pack_bf16rn(vv[12], vv[13]), pack_bf16rn(vv[14], vv[15]));
        *(uint4*)vp = p0;
        *(uint4*)(vp + 8) = p1;
    }
}

// ---------------- Kernel B: barrier-free flash attention ----------------
// grid 512: b = blockIdx&63 (XCD affinity), qh = blockIdx>>6 (128-q block).
// 4 waves x 32 queries (2 strips of 16). K/V frags direct from global.
__global__ __launch_bounds__(256, 2) void attn_kernel(
    const unsigned short* __restrict__ qs,
    const unsigned short* __restrict__ ksc,
    const unsigned short* __restrict__ vt,
    float* __restrict__ out)
{
    __shared__ short Pl[4][32][72];    // per-wave P buffer only (18.4 KB)

    const int t    = threadIdx.x;
    const int wave = t >> 6;
    const int lane = t & 63;
    const int l16  = lane & 15;
    const int quad = lane >> 4;
    const int b    = blockIdx.x & 63;
    const int qh   = blockIdx.x >> 6;
    const int qbase = qh * 128 + wave * 32;

    const unsigned short* kb_ = ksc + (long)b * (Nsz * Dsz);
    const unsigned short* vb_ = vt  + (long)b * (Dsz * Nsz);

    // Q A-frags: strip s rows = qbase + s*16 + l16
    short8 aq[2][2];
    #pragma unroll
    for (int s = 0; s < 2; s++) {
        const unsigned short* qp = qs + ((long)b * Nsz + qbase + s * 16 + l16) * Dsz + quad * 8;
        aq[s][0] = *(const short8*)(qp);
        aq[s][1] = *(const short8*)(qp + 32);
    }

    f32x4 O[2][4];
    float lsum[2][4];
    #pragma unroll
    for (int s = 0; s < 2; s++) {
        #pragma unroll
        for (int i = 0; i < 4; i++) { O[s][i] = (f32x4){0.f, 0.f, 0.f, 0.f}; lsum[s][i] = 0.f; }
    }

    // prefetch K-frags for kt=0
    short8 kf[4][2];
    #pragma unroll
    for (int kb = 0; kb < 4; kb++) {
        const unsigned short* p = kb_ + (long)(kb * 16 + l16) * Dsz + quad * 8;
        kf[kb][0] = *(const short8*)(p);
        kf[kb][1] = *(const short8*)(p + 32);
    }

    for (int kt = 0; kt < 16; kt++) {
        // V^T frags for this kt issued early (hide under QK+softmax)
        short8 bvf[2][4];
        #pragma unroll
        for (int ck = 0; ck < 2; ck++) {
            #pragma unroll
            for (int cb = 0; cb < 4; cb++) {
                bvf[ck][cb] = *(const short8*)(vb_ + (long)(cb * 16 + l16) * Nsz
                                               + kt * 64 + ck * 32 + quad * 8);
            }
        }

        // per strip: S = q K^T, P = 2^S, write Pl (pi-packed b64)
        #pragma unroll
        for (int s = 0; s < 2; s++) {
            f32x4 sc[4];
            #pragma unroll
            for (int kb = 0; kb < 4; kb++) {
                f32x4 z = (f32x4){0.f, 0.f, 0.f, 0.f};
                z = __builtin_amdgcn_mfma_f32_16x16x32_bf16(aq[s][0], kf[kb][0], z, 0, 0, 0);
                z = __builtin_amdgcn_mfma_f32_16x16x32_bf16(aq[s][1], kf[kb][1], z, 0, 0, 0);
                sc[kb] = z;
            }
            #pragma unroll
            for (int r = 0; r < 4; r++) {
                float p0 = __builtin_amdgcn_exp2f(sc[0][r]);
                float p1 = __builtin_amdgcn_exp2f(sc[1][r]);
                float p2 = __builtin_amdgcn_exp2f(sc[2][r]);
                float p3 = __builtin_amdgcn_exp2f(sc[3][r]);
                lsum[s][r] += (p0 + p1) + (p2 + p3);
                unsigned pk01 = pack_bf16rn(p0, p1);
                unsigned pk23 = pack_bf16rn(p2, p3);
                *(uint2*)&Pl[wave][s * 16 + quad * 4 + r][l16 * 4] = make_uint2(pk01, pk23);
            }
        }

        // prefetch next kt's K-frags (hide under PV)
        short8 kf2[4][2];
        {
            int ktn = (kt + 1) & 15;
            #pragma unroll
            for (int kb = 0; kb < 4; kb++) {
                const unsigned short* p = kb_ + (long)(ktn * 64 + kb * 16 + l16) * Dsz + quad * 8;
                kf2[kb][0] = *(const short8*)(p);
                kf2[kb][1] = *(const short8*)(p + 32);
            }
        }

        // O += P V  (Pl read in A-layout; within-wave, no barrier)
        #pragma unroll
        for (int ck = 0; ck < 2; ck++) {
            #pragma unroll
            for (int s = 0; s < 2; s++) {
                short8 ap = *(const short8*)&Pl[wave][s * 16 + l16][ck * 32 + quad * 8];
                #pragma unroll
                for (int cb = 0; cb < 4; cb++) {
                    O[s][cb] = __builtin_amdgcn_mfma_f32_16x16x32_bf16(ap, bvf[ck][cb], O[s][cb], 0, 0, 0);
                }
            }
        }

        #pragma unroll
        for (int kb = 0; kb < 4; kb++) { kf[kb][0] = kf2[kb][0]; kf[kb][1] = kf2[kb][1]; }
    }

    // row-sum reduce (lanes sharing a row = same quad, l16 0..15)
    #pragma unroll
    for (int s = 0; s < 2; s++) {
        #pragma unroll
        for (int r = 0; r < 4; r++) {
            #pragma unroll
            for (int off = 1; off < 16; off <<= 1)
                lsum[s][r] += __shfl_xor(lsum[s][r], off);
        }
    }

    // epilogue: out = O/l + q  (q reconstructed from bf16 scaled copy)
    #pragma unroll
    for (int s = 0; s < 2; s++) {
        #pragma unroll
        for (int r = 0; r < 4; r++) {
            float rl = 1.0f / lsum[s][r];
            long nrow = (long)b * Nsz + qbase + s * 16 + quad * 4 + r;
            #pragma unroll
            for (int cb = 0; cb < 4; cb++) {
                int d = cb * 16 + l16;
                float qv = bf2f(qs[nrow * Dsz + d]) * INV_SC;
                out[nrow * Dsz + d] = O[s][cb][r] * rl + qv;
            }
        }
    }
}

extern "C" void kernel_launch(void* const* d_in, const int* in_sizes, int n_in,
                              void* d_out, int out_size, void* d_ws, size_t ws_size,
                              hipStream_t stream) {
    const float* x  = (const float*)d_in[0];
    const float* Wq = (const float*)d_in[1];
    const float* bq = (const float*)d_in[2];
    const float* Wk = (const float*)d_in[3];
    const float* bk = (const float*)d_in[4];
    const float* Wv = (const float*)d_in[5];
    const float* bv = (const float*)d_in[6];
    float* out = (float*)d_out;

    char* ws = (char*)d_ws;
    unsigned short* qsc = (unsigned short*)ws;                 // 8 MB bf16 q*SC
    unsigned short* ksc = (unsigned short*)(ws + 0x1000000);   // 8 MB bf16 k
    unsigned short* vtc = (unsigned short*)(ws + 0x2000000);   // 8 MB bf16 v^T pi-permuted

    qkv_kernel<<<dim3(512), dim3(256), 0, stream>>>(
        x, Wq, bq, Wk, bk, Wv, bv, qsc, ksc, vtc);
    attn_kernel<<<dim3(512), dim3(256), 0, stream>>>(
        qsc, ksc, vtc, out);
}

// Round 4
// 126.919 us; speedup vs baseline: 1.2614x; 1.2614x over previous
//
#include <hip/hip_runtime.h>
#include <hip/hip_bf16.h>

// SelfAttentionLayer: B=64, N=1024, C=128, D=64
// R3: attn back to block-cooperative LDS staging (R2's direct-global loads
// were latency-bound at 2 waves/SIMD), now async via global_load_lds w=16,
// double-buffered, ONE barrier/kt with issue-AFTER-barrier so the drain only
// waits on compute-phase-old DMA. XOR slot swizzle keeps b128 frag reads at
// the 8-lane/group optimum. qkv: weights pre-converted to B-frag layout by
// wprep kernel -> 16 b128 loads/thread instead of 128 scalar gathers.

#define Bsz 64
#define Nsz 1024
#define Csz 128
#define Dsz 64

typedef __attribute__((ext_vector_type(8))) short short8;
typedef __attribute__((ext_vector_type(4))) float f32x4;

__device__ __forceinline__ unsigned short f2bf(float f) {
    union { float f; unsigned u; } v; v.f = f;
    unsigned r = v.u + 0x7FFF + ((v.u >> 16) & 1);
    return (unsigned short)(r >> 16);
}
__device__ __forceinline__ float bf2f(unsigned short h) {
    union { unsigned u; float f; } v; v.u = ((unsigned)h) << 16;
    return v.f;
}
__device__ __forceinline__ unsigned pack_bf16rn(float lo, float hi) {
    unsigned ulo = __float_as_uint(lo) + 0x8000u;
    unsigned uhi = __float_as_uint(hi) + 0x8000u;
    return __builtin_amdgcn_perm(uhi, ulo, 0x07060302u);
}
// async global->LDS DMA, 16B/lane; LDS dest = uniform base + lane*16
__device__ __forceinline__ void gl_lds16(const void* gsrc, void* ldst) {
    __builtin_amdgcn_global_load_lds(
        (const __attribute__((address_space(1))) unsigned int*)gsrc,
        (__attribute__((address_space(3))) unsigned int*)ldst, 16, 0, 0);
}

#define SCq (0.125f * 1.44269504f)     // 1/sqrt(D) * log2(e) folded into qs
#define INV_SC (1.0f / (0.125f * 1.44269504f))

// ---------------- Kernel 0: weight prep -> B-frag layout bf16 ----------------
// wfrag: [mat:{qh,ql,k,v}][dt*4+ksi][lane][8] shorts, 4*8192 shorts total
__global__ __launch_bounds__(256) void wprep_kernel(
    const float* __restrict__ Wq, const float* __restrict__ Wk,
    const float* __restrict__ Wv, unsigned short* __restrict__ wfrag)
{
    int t = blockIdx.x * 256 + threadIdx.x;   // 0..1023 = (dt,ksi,lane)
    int lane = t & 63, ksi = (t >> 6) & 3, dt = t >> 8;
    int l16 = lane & 15, quad = lane >> 4;
    int d = dt * 16 + l16;
    int c0 = ksi * 32 + quad * 8;
    short8 h8, l8, k8, v8;
    #pragma unroll
    for (int j = 0; j < 8; j++) {
        float w = Wq[(c0 + j) * Dsz + d];
        unsigned short h = f2bf(w);
        h8[j] = (short)h;
        l8[j] = (short)f2bf(w - bf2f(h));
        k8[j] = (short)f2bf(Wk[(c0 + j) * Dsz + d]);
        v8[j] = (short)f2bf(Wv[(c0 + j) * Dsz + d]);
    }
    int idx = (dt * 4 + ksi) * 64 + lane;
    ((short8*)wfrag)[0 * 1024 + idx] = h8;
    ((short8*)wfrag)[1 * 1024 + idx] = l8;
    ((short8*)wfrag)[2 * 1024 + idx] = k8;
    ((short8*)wfrag)[3 * 1024 + idx] = v8;
}

// ---------------- Kernel A: QKV projection via MFMA ----------------
// grid 512 x 256 thr; block = 128 rows (2 chunks of 64); wave = d-tile.
__global__ __launch_bounds__(256) void qkv_kernel(
    const float* __restrict__ x, const unsigned short* __restrict__ wfrag,
    const float* __restrict__ bq, const float* __restrict__ bk,
    const float* __restrict__ bv,
    unsigned short* __restrict__ qs, unsigned short* __restrict__ ksc,
    unsigned short* __restrict__ vt)
{
    __shared__ short xh[8192];   // [4 rt][4 ks][64 lane][8] A-frag layout
    __shared__ short xl[8192];
    const int t    = threadIdx.x;
    const int lane = t & 63;
    const int l16  = lane & 15, quad = lane >> 4;
    const int dt   = t >> 6;
    const long rowbase = (long)blockIdx.x * 128;
    const int d = dt * 16 + l16;

    // ---- weight B-frags: 16 coalesced b128 loads ----
    short8 wqh[4], wql[4], wkf[4], wvf[4];
    #pragma unroll
    for (int ksi = 0; ksi < 4; ksi++) {
        int idx = (dt * 4 + ksi) * 64 + lane;
        wqh[ksi] = ((const short8*)wfrag)[0 * 1024 + idx];
        wql[ksi] = ((const short8*)wfrag)[1 * 1024 + idx];
        wkf[ksi] = ((const short8*)wfrag)[2 * 1024 + idx];
        wvf[ksi] = ((const short8*)wfrag)[3 * 1024 + idx];
    }
    const float bqd = bq[d], bkd = bk[d], bvd = bv[d];
    const long b = rowbase >> 10;

    for (int chunk = 0; chunk < 2; chunk++) {
        const long rowc = rowbase + chunk * 64;
        if (chunk) __syncthreads();

        // ---- stage x chunk -> bf16 hi/lo in A-frag layout ----
        {
            const int row = t & 63;
            const float* xrow = x + (rowc + row) * Csz;
            #pragma unroll
            for (int p = 0; p < 4; p++) {
                int cb = (t >> 6) + p * 4;
                float4 a = *(const float4*)(xrow + cb * 8);
                float4 bb = *(const float4*)(xrow + cb * 8 + 4);
                float f[8] = {a.x, a.y, a.z, a.w, bb.x, bb.y, bb.z, bb.w};
                short8 hi, lo;
                #pragma unroll
                for (int i = 0; i < 8; i++) {
                    unsigned short h = f2bf(f[i]);
                    hi[i] = (short)h;
                    lo[i] = (short)f2bf(f[i] - bf2f(h));
                }
                int unit = ((row >> 4) * 4 + (cb >> 2)) * 64 + ((row & 15) | ((cb & 3) << 4));
                *(short8*)&xh[unit * 8] = hi;
                *(short8*)&xl[unit * 8] = lo;
            }
        }
        __syncthreads();

        f32x4 aq[4], ak[4], av[4];
        #pragma unroll
        for (int i = 0; i < 4; i++) {
            aq[i] = (f32x4){0.f, 0.f, 0.f, 0.f};
            ak[i] = (f32x4){0.f, 0.f, 0.f, 0.f};
            av[i] = (f32x4){0.f, 0.f, 0.f, 0.f};
        }
        #pragma unroll
        for (int ksi = 0; ksi < 4; ksi++) {
            #pragma unroll
            for (int rt = 0; rt < 4; rt++) {
                short8 ah = *(const short8*)&xh[((rt * 4 + ksi) * 64 + lane) * 8];
                short8 al = *(const short8*)&xl[((rt * 4 + ksi) * 64 + lane) * 8];
                aq[rt] = __builtin_amdgcn_mfma_f32_16x16x32_bf16(ah, wqh[ksi], aq[rt], 0, 0, 0);
                aq[rt] = __builtin_amdgcn_mfma_f32_16x16x32_bf16(al, wqh[ksi], aq[rt], 0, 0, 0);
                aq[rt] = __builtin_amdgcn_mfma_f32_16x16x32_bf16(ah, wql[ksi], aq[rt], 0, 0, 0);
                ak[rt] = __builtin_amdgcn_mfma_f32_16x16x32_bf16(ah, wkf[ksi], ak[rt], 0, 0, 0);
                av[rt] = __builtin_amdgcn_mfma_f32_16x16x32_bf16(ah, wvf[ksi], av[rt], 0, 0, 0);
            }
        }

        // ---- epilogue ----
        float vv[16];
        #pragma unroll
        for (int rt = 0; rt < 4; rt++) {
            #pragma unroll
            for (int r = 0; r < 4; r++) {
                long n = rowc + rt * 16 + quad * 4 + r;
                float q = fmaxf(aq[rt][r] + bqd, 0.f);
                float k = fmaxf(ak[rt][r] + bkd, 0.f);
                float v = fmaxf(av[rt][r] + bvd, 0.f);
                qs[n * Dsz + d]  = f2bf(q * SCq);
                ksc[n * Dsz + d] = f2bf(k);
                vv[r * 4 + rt] = v;   // pi(n&63) = (n&15)*4 + (n>>4)
            }
        }
        unsigned short* vp = vt + b * (Dsz * Nsz) + (long)d * Nsz + (rowc & 1023) + quad * 16;
        uint4 p0 = make_uint4(pack_bf16rn(vv[0], vv[1]),  pack_bf16rn(vv[2], vv[3]),
                              pack_bf16rn(vv[4], vv[5]),  pack_bf16rn(vv[6], vv[7]));
        uint4 p1 = make_uint4(pack_bf16rn(vv[8], vv[9]),  pack_bf16rn(vv[10], vv[11]),
                              pack_bf16rn(vv[12], vv[13]), pack_bf16rn(vv[14], vv[15]));
        *(uint4*)vp = p0;
        *(uint4*)(vp + 8) = p1;
    }
}

// ---------------- Kernel B: pipelined flash attention ----------------
// grid 512: b = blk&63 (XCD affinity), qh = blk>>6. 4 waves x 32 q.
// K/V tiles: async DMA double-buffer, XOR-swizzled slots, 1 barrier/kt.
__global__ __launch_bounds__(256) void attn_kernel(
    const unsigned short* __restrict__ qs,
    const unsigned short* __restrict__ ksc,
    const unsigned short* __restrict__ vt,
    float* __restrict__ out)
{
    __shared__ short tiles[4][4096];   // [buf*2 + (0=K,1=V)][512 slots x 8 shorts]
    __shared__ short Pl[4][32][72];    // per-wave P (C->A layout round-trip)

    const int t    = threadIdx.x;
    const int wave = t >> 6;
    const int lane = t & 63;
    const int l16  = lane & 15;
    const int quad = lane >> 4;
    const int b    = blockIdx.x & 63;
    const int qh   = blockIdx.x >> 6;
    const int qbase = qh * 128 + wave * 32;

    const unsigned short* kb_ = ksc + (long)b * (Nsz * Dsz);
    const unsigned short* vb_ = vt  + (long)b * (Dsz * Nsz);

    // DMA issue for one tile: 2 K-calls + 2 V-calls per wave
    auto issue = [&](int kt, int bufi) {
        const unsigned short* kg = kb_ + (long)kt * 64 * Dsz;
        const unsigned short* vg = vb_ + kt * 64;
        #pragma unroll
        for (int i = 0; i < 2; i++) {
            int seg  = wave * 2 + i;               // 0..7
            int slot = seg * 64 + lane;
            int rw = slot >> 3, pc = slot & 7, c = pc ^ (rw & 7);
            gl_lds16(kg + rw * Dsz + c * 8, &tiles[bufi * 2][seg * 512]);
            gl_lds16(vg + (long)rw * Nsz + c * 8, &tiles[bufi * 2 + 1][seg * 512]);
        }
    };

    // Q A-frags
    short8 aq[2][2];
    #pragma unroll
    for (int s = 0; s < 2; s++) {
        const unsigned short* qp = qs + ((long)b * Nsz + qbase + s * 16 + l16) * Dsz + quad * 8;
        aq[s][0] = *(const short8*)(qp);
        aq[s][1] = *(const short8*)(qp + 32);
    }

    f32x4 O[2][4];
    float lsum[2][4];
    #pragma unroll
    for (int s = 0; s < 2; s++)
        #pragma unroll
        for (int i = 0; i < 4; i++) { O[s][i] = (f32x4){0.f,0.f,0.f,0.f}; lsum[s][i] = 0.f; }

    issue(0, 0);

    for (int kt = 0; kt < 16; kt++) {
        const int cur = kt & 1;
        __syncthreads();                      // drains tile-kt DMA (compute-phase old)
        if (kt < 15) issue(kt + 1, 1 - cur);  // after barrier: overwrite-safe, flies under compute

        const short* Kt  = &tiles[cur * 2][0];
        const short* Vtl = &tiles[cur * 2 + 1][0];

        // K frags (shared by both strips); V frags issued early for latency
        short8 kf[4][2];
        #pragma unroll
        for (int kb = 0; kb < 4; kb++) {
            int row = kb * 16 + l16;
            kf[kb][0] = *(const short8*)(Kt + (row * 8 + ( quad      ^ (l16 & 7))) * 8);
            kf[kb][1] = *(const short8*)(Kt + (row * 8 + ((4 + quad) ^ (l16 & 7))) * 8);
        }
        short8 bvf[2][4];
        #pragma unroll
        for (int ck = 0; ck < 2; ck++) {
            #pragma unroll
            for (int cb = 0; cb < 4; cb++) {
                int dim = cb * 16 + l16;
                bvf[ck][cb] = *(const short8*)(Vtl + (dim * 8 + ((ck * 4 + quad) ^ (l16 & 7))) * 8);
            }
        }

        // per strip: S = q K^T, P = 2^S, Pl write (pi-packed b64)
        #pragma unroll
        for (int s = 0; s < 2; s++) {
            f32x4 sc[4];
            #pragma unroll
            for (int kb = 0; kb < 4; kb++) {
                f32x4 z = (f32x4){0.f, 0.f, 0.f, 0.f};
                z = __builtin_amdgcn_mfma_f32_16x16x32_bf16(aq[s][0], kf[kb][0], z, 0, 0, 0);
                z = __builtin_amdgcn_mfma_f32_16x16x32_bf16(aq[s][1], kf[kb][1], z, 0, 0, 0);
                sc[kb] = z;
            }
            #pragma unroll
            for (int r = 0; r < 4; r++) {
                float p0 = __builtin_amdgcn_exp2f(sc[0][r]);
                float p1 = __builtin_amdgcn_exp2f(sc[1][r]);
                float p2 = __builtin_amdgcn_exp2f(sc[2][r]);
                float p3 = __builtin_amdgcn_exp2f(sc[3][r]);
                lsum[s][r] += (p0 + p1) + (p2 + p3);
                *(uint2*)&Pl[wave][s * 16 + quad * 4 + r][l16 * 4] =
                    make_uint2(pack_bf16rn(p0, p1), pack_bf16rn(p2, p3));
            }
        }

        // O += P V (within-wave Pl read in A-layout)
        #pragma unroll
        for (int ck = 0; ck < 2; ck++) {
            #pragma unroll
            for (int s = 0; s < 2; s++) {
                short8 ap = *(const short8*)&Pl[wave][s * 16 + l16][ck * 32 + quad * 8];
                #pragma unroll
                for (int cb = 0; cb < 4; cb++) {
                    O[s][cb] = __builtin_amdgcn_mfma_f32_16x16x32_bf16(ap, bvf[ck][cb], O[s][cb], 0, 0, 0);
                }
            }
        }
    }

    // deferred row-sum reduction
    #pragma unroll
    for (int s = 0; s < 2; s++)
        #pragma unroll
        for (int r = 0; r < 4; r++)
            #pragma unroll
            for (int off = 1; off < 16; off <<= 1)
                lsum[s][r] += __shfl_xor(lsum[s][r], off);

    // epilogue: out = O/l + q (q from bf16 scaled copy)
    #pragma unroll
    for (int s = 0; s < 2; s++) {
        #pragma unroll
        for (int r = 0; r < 4; r++) {
            float rl = 1.0f / lsum[s][r];
            long nrow = (long)b * Nsz + qbase + s * 16 + quad * 4 + r;
            #pragma unroll
            for (int cb = 0; cb < 4; cb++) {
                int d = cb * 16 + l16;
                float qv = bf2f(qs[nrow * Dsz + d]) * INV_SC;
                out[nrow * Dsz + d] = O[s][cb][r] * rl + qv;
            }
        }
    }
}

extern "C" void kernel_launch(void* const* d_in, const int* in_sizes, int n_in,
                              void* d_out, int out_size, void* d_ws, size_t ws_size,
                              hipStream_t stream) {
    const float* x  = (const float*)d_in[0];
    const float* Wq = (const float*)d_in[1];
    const float* bq = (const float*)d_in[2];
    const float* Wk = (const float*)d_in[3];
    const float* bk = (const float*)d_in[4];
    const float* Wv = (const float*)d_in[5];
    const float* bv = (const float*)d_in[6];
    float* out = (float*)d_out;

    char* ws = (char*)d_ws;
    unsigned short* qsc   = (unsigned short*)ws;                 // 8 MB bf16 q*SC
    unsigned short* kscp  = (unsigned short*)(ws + 0x1000000);   // 8 MB bf16 k
    unsigned short* vtc   = (unsigned short*)(ws + 0x2000000);   // 8 MB bf16 v^T pi
    unsigned short* wfrag = (unsigned short*)(ws + 0x3000000);   // 64 KB W frags

    wprep_kernel<<<dim3(4), dim3(256), 0, stream>>>(Wq, Wk, Wv, wfrag);
    qkv_kernel<<<dim3(512), dim3(256), 0, stream>>>(
        x, wfrag, bq, bk, bv, qsc, kscp, vtc);
    attn_kernel<<<dim3(512), dim3(256), 0, stream>>>(
        qsc, kscp, vtc, out);
}

// Round 5
// 121.842 us; speedup vs baseline: 1.3139x; 1.0417x over previous
//
#include <hip/hip_runtime.h>
#include <hip/hip_bf16.h>

// SelfAttentionLayer: B=64, N=1024, C=128, D=64
// R4: frag-major K/V workspace layouts -> attn loads every MFMA B-fragment
// as ONE coalesced 1KB global instruction from L2 (R2's barrier-free concept,
// minus R2's fatal 64-lines-per-instr uncoalesced reads). attn has zero
// block staging, zero __syncthreads; K-frags register-double-buffered.
// qkv: grid 1024 (64-row blocks, 4/CU); K stores = same 16 scalar b16 cost
// as before but frag-scattered; V^T stores stay packed b128.

#define Bsz 64
#define Nsz 1024
#define Csz 128
#define Dsz 64

typedef __attribute__((ext_vector_type(8))) short short8;
typedef __attribute__((ext_vector_type(4))) float f32x4;

__device__ __forceinline__ unsigned short f2bf(float f) {
    union { float f; unsigned u; } v; v.f = f;
    unsigned r = v.u + 0x7FFF + ((v.u >> 16) & 1);
    return (unsigned short)(r >> 16);
}
__device__ __forceinline__ float bf2f(unsigned short h) {
    union { unsigned u; float f; } v; v.u = ((unsigned)h) << 16;
    return v.f;
}
__device__ __forceinline__ unsigned pack_bf16rn(float lo, float hi) {
    unsigned ulo = __float_as_uint(lo) + 0x8000u;
    unsigned uhi = __float_as_uint(hi) + 0x8000u;
    return __builtin_amdgcn_perm(uhi, ulo, 0x07060302u);
}

#define SCq (0.125f * 1.44269504f)     // 1/sqrt(D) * log2(e) folded into qs
#define INV_SC (1.0f / (0.125f * 1.44269504f))

// ---------------- Kernel 0: weight prep -> B-frag layout bf16 ----------------
__global__ __launch_bounds__(256) void wprep_kernel(
    const float* __restrict__ Wq, const float* __restrict__ Wk,
    const float* __restrict__ Wv, unsigned short* __restrict__ wfrag)
{
    int t = blockIdx.x * 256 + threadIdx.x;   // 0..1023 = (dt,ksi,lane)
    int lane = t & 63, ksi = (t >> 6) & 3, dt = t >> 8;
    int l16 = lane & 15, quad = lane >> 4;
    int d = dt * 16 + l16;
    int c0 = ksi * 32 + quad * 8;
    short8 h8, l8, k8, v8;
    #pragma unroll
    for (int j = 0; j < 8; j++) {
        float w = Wq[(c0 + j) * Dsz + d];
        unsigned short h = f2bf(w);
        h8[j] = (short)h;
        l8[j] = (short)f2bf(w - bf2f(h));
        k8[j] = (short)f2bf(Wk[(c0 + j) * Dsz + d]);
        v8[j] = (short)f2bf(Wv[(c0 + j) * Dsz + d]);
    }
    int idx = (dt * 4 + ksi) * 64 + lane;
    ((short8*)wfrag)[0 * 1024 + idx] = h8;
    ((short8*)wfrag)[1 * 1024 + idx] = l8;
    ((short8*)wfrag)[2 * 1024 + idx] = k8;
    ((short8*)wfrag)[3 * 1024 + idx] = v8;
}

// ---------------- Kernel A: QKV projection via MFMA ----------------
// grid 1024 x 256; block = 64 rows; wave = d-tile dt.
// Outputs: qs[n][d] bf16 (scaled), ks2/vt2 in frag-major layouts:
//   ks2 short8-index: (((b*16+kt)*4 + kb)*2 + half)*64 + lane
//   vt2 short8-index: (((b*16+kt)*4 + cb)*2 + ck  )*64 + lane
__global__ __launch_bounds__(256) void qkv_kernel(
    const float* __restrict__ x, const unsigned short* __restrict__ wfrag,
    const float* __restrict__ bq, const float* __restrict__ bk,
    const float* __restrict__ bv,
    unsigned short* __restrict__ qs, unsigned short* __restrict__ ks2,
    unsigned short* __restrict__ vt2)
{
    __shared__ short xh[8192];   // [4 rt][4 ks][64 lane][8] A-frag layout
    __shared__ short xl[8192];
    const int t    = threadIdx.x;
    const int lane = t & 63;
    const int l16  = lane & 15, quad = lane >> 4;
    const int dt   = t >> 6;
    const long rowbase = (long)blockIdx.x * 64;
    const int d = dt * 16 + l16;

    // weight B-frags: 16 coalesced b128 loads (L2-hot wfrag)
    short8 wqh[4], wql[4], wkf[4], wvf[4];
    #pragma unroll
    for (int ksi = 0; ksi < 4; ksi++) {
        int idx = (dt * 4 + ksi) * 64 + lane;
        wqh[ksi] = ((const short8*)wfrag)[0 * 1024 + idx];
        wql[ksi] = ((const short8*)wfrag)[1 * 1024 + idx];
        wkf[ksi] = ((const short8*)wfrag)[2 * 1024 + idx];
        wvf[ksi] = ((const short8*)wfrag)[3 * 1024 + idx];
    }

    // stage x -> bf16 hi/lo in A-frag layout
    {
        const int row = t & 63;
        const float* xrow = x + (rowbase + row) * Csz;
        #pragma unroll
        for (int p = 0; p < 4; p++) {
            int cb = (t >> 6) + p * 4;
            float4 a = *(const float4*)(xrow + cb * 8);
            float4 bb = *(const float4*)(xrow + cb * 8 + 4);
            float f[8] = {a.x, a.y, a.z, a.w, bb.x, bb.y, bb.z, bb.w};
            short8 hi, lo;
            #pragma unroll
            for (int i = 0; i < 8; i++) {
                unsigned short h = f2bf(f[i]);
                hi[i] = (short)h;
                lo[i] = (short)f2bf(f[i] - bf2f(h));
            }
            int unit = ((row >> 4) * 4 + (cb >> 2)) * 64 + ((row & 15) | ((cb & 3) << 4));
            *(short8*)&xh[unit * 8] = hi;
            *(short8*)&xl[unit * 8] = lo;
        }
    }
    __syncthreads();

    f32x4 aq[4], ak[4], av[4];
    #pragma unroll
    for (int i = 0; i < 4; i++) {
        aq[i] = (f32x4){0.f, 0.f, 0.f, 0.f};
        ak[i] = (f32x4){0.f, 0.f, 0.f, 0.f};
        av[i] = (f32x4){0.f, 0.f, 0.f, 0.f};
    }
    #pragma unroll
    for (int ksi = 0; ksi < 4; ksi++) {
        #pragma unroll
        for (int rt = 0; rt < 4; rt++) {
            short8 ah = *(const short8*)&xh[((rt * 4 + ksi) * 64 + lane) * 8];
            short8 al = *(const short8*)&xl[((rt * 4 + ksi) * 64 + lane) * 8];
            aq[rt] = __builtin_amdgcn_mfma_f32_16x16x32_bf16(ah, wqh[ksi], aq[rt], 0, 0, 0);
            aq[rt] = __builtin_amdgcn_mfma_f32_16x16x32_bf16(al, wqh[ksi], aq[rt], 0, 0, 0);
            aq[rt] = __builtin_amdgcn_mfma_f32_16x16x32_bf16(ah, wql[ksi], aq[rt], 0, 0, 0);
            ak[rt] = __builtin_amdgcn_mfma_f32_16x16x32_bf16(ah, wkf[ksi], ak[rt], 0, 0, 0);
            av[rt] = __builtin_amdgcn_mfma_f32_16x16x32_bf16(ah, wvf[ksi], av[rt], 0, 0, 0);
        }
    }

    // ---- epilogue ----
    const float bqd = bq[d], bkd = bk[d], bvd = bv[d];
    const long b  = rowbase >> 10;
    const int  kt = (int)((rowbase >> 6) & 15);

    // K frag-scatter constants: value(n,d) -> frag (kb=rt, half, lane=quadk*16+quad*4+r, j)
    const int half  = dt >> 1;
    const int quadk = ((dt & 1) << 1) | (l16 >> 3);
    const int jk    = l16 & 7;
    unsigned short* kbase = ks2 + ((((long)(b * 16 + kt) * 4) * 2 + half) * 64) * 8;

    float vv[4][4];   // [r][rt]
    #pragma unroll
    for (int rt = 0; rt < 4; rt++) {
        #pragma unroll
        for (int r = 0; r < 4; r++) {
            long n = rowbase + rt * 16 + quad * 4 + r;
            float q = fmaxf(aq[rt][r] + bqd, 0.f);
            float k = fmaxf(ak[rt][r] + bkd, 0.f);
            vv[r][rt] = fmaxf(av[rt][r] + bvd, 0.f);
            qs[n * Dsz + d] = f2bf(q * SCq);
            kbase[((long)rt * 2 * 64 + quadk * 16 + quad * 4 + r) * 8 + jk] = f2bf(k);
        }
    }
    // V frag-major stores: 2 x b128. lane slot = quadp*16 + l16, shorts j=r*4+rt (mod 8)
    const int ck = quad >> 1;
    const int quadp = (quad & 1) * 2;
    long vidx = (((long)(b * 16 + kt) * 4 + dt) * 2 + ck) * 64 + quadp * 16 + l16;
    uint4 o0 = make_uint4(pack_bf16rn(vv[0][0], vv[0][1]), pack_bf16rn(vv[0][2], vv[0][3]),
                          pack_bf16rn(vv[1][0], vv[1][1]), pack_bf16rn(vv[1][2], vv[1][3]));
    uint4 o1 = make_uint4(pack_bf16rn(vv[2][0], vv[2][1]), pack_bf16rn(vv[2][2], vv[2][3]),
                          pack_bf16rn(vv[3][0], vv[3][1]), pack_bf16rn(vv[3][2], vv[3][3]));
    ((uint4*)vt2)[vidx]      = o0;
    ((uint4*)vt2)[vidx + 16] = o1;
}

// ---------------- Kernel B: barrier-free flash attention ----------------
// grid 512: b = blk&63 (XCD L2 affinity), qh = blk>>6. 4 waves x 32 q.
// All K/V frag loads are coalesced 1KB b128s from frag-major layouts.
__global__ __launch_bounds__(256) void attn_kernel(
    const unsigned short* __restrict__ qs,
    const unsigned short* __restrict__ ks2,
    const unsigned short* __restrict__ vt2,
    float* __restrict__ out)
{
    __shared__ short Pl[4][32][72];    // per-wave P (C->A layout round-trip)

    const int t    = threadIdx.x;
    const int wave = t >> 6;
    const int lane = t & 63;
    const int l16  = lane & 15;
    const int quad = lane >> 4;
    const int b    = blockIdx.x & 63;
    const int qh   = blockIdx.x >> 6;
    const int qbase = qh * 128 + wave * 32;

    const short8* ks8 = (const short8*)ks2 + (long)b * (16 * 4 * 2 * 64);
    const short8* vt8 = (const short8*)vt2 + (long)b * (16 * 4 * 2 * 64);

    // Q A-frags
    short8 aq[2][2];
    #pragma unroll
    for (int s = 0; s < 2; s++) {
        const unsigned short* qp = qs + ((long)b * Nsz + qbase + s * 16 + l16) * Dsz + quad * 8;
        aq[s][0] = *(const short8*)(qp);
        aq[s][1] = *(const short8*)(qp + 32);
    }

    f32x4 O[2][4];
    float lsum[2][4];
    #pragma unroll
    for (int s = 0; s < 2; s++)
        #pragma unroll
        for (int i = 0; i < 4; i++) { O[s][i] = (f32x4){0.f,0.f,0.f,0.f}; lsum[s][i] = 0.f; }

    // preload K-frags for kt=0: frag idx (kb*2+half)*64 + lane
    short8 kf[4][2];
    #pragma unroll
    for (int kb = 0; kb < 4; kb++) {
        kf[kb][0] = ks8[(kb * 2 + 0) * 64 + lane];
        kf[kb][1] = ks8[(kb * 2 + 1) * 64 + lane];
    }

    for (int kt = 0; kt < 16; kt++) {
        // V frags for this kt — issued first, consumed ~400 cyc later at PV
        short8 bvf[2][4];
        #pragma unroll
        for (int cb = 0; cb < 4; cb++) {
            bvf[0][cb] = vt8[((long)kt * 8 + cb * 2 + 0) * 64 + lane];
            bvf[1][cb] = vt8[((long)kt * 8 + cb * 2 + 1) * 64 + lane];
        }

        // S = q K^T per strip
        f32x4 sc[2][4];
        #pragma unroll
        for (int s = 0; s < 2; s++) {
            #pragma unroll
            for (int kb = 0; kb < 4; kb++) {
                f32x4 z = (f32x4){0.f, 0.f, 0.f, 0.f};
                z = __builtin_amdgcn_mfma_f32_16x16x32_bf16(aq[s][0], kf[kb][0], z, 0, 0, 0);
                z = __builtin_amdgcn_mfma_f32_16x16x32_bf16(aq[s][1], kf[kb][1], z, 0, 0, 0);
                sc[s][kb] = z;
            }
        }

        // prefetch next kt's K-frags (independent; flies under exp+PV)
        short8 kf2[4][2];
        {
            int ktn = (kt + 1) & 15;
            #pragma unroll
            for (int kb = 0; kb < 4; kb++) {
                kf2[kb][0] = ks8[((long)ktn * 8 + kb * 2 + 0) * 64 + lane];
                kf2[kb][1] = ks8[((long)ktn * 8 + kb * 2 + 1) * 64 + lane];
            }
        }

        // P = 2^S, pi-packed b64 into per-wave Pl
        #pragma unroll
        for (int s = 0; s < 2; s++) {
            #pragma unroll
            for (int r = 0; r < 4; r++) {
                float p0 = __builtin_amdgcn_exp2f(sc[s][0][r]);
                float p1 = __builtin_amdgcn_exp2f(sc[s][1][r]);
                float p2 = __builtin_amdgcn_exp2f(sc[s][2][r]);
                float p3 = __builtin_amdgcn_exp2f(sc[s][3][r]);
                lsum[s][r] += (p0 + p1) + (p2 + p3);
                *(uint2*)&Pl[wave][s * 16 + quad * 4 + r][l16 * 4] =
                    make_uint2(pack_bf16rn(p0, p1), pack_bf16rn(p2, p3));
            }
        }

        // O += P V (within-wave Pl read in A-layout; lgkmcnt only, no barrier)
        #pragma unroll
        for (int ck = 0; ck < 2; ck++) {
            #pragma unroll
            for (int s = 0; s < 2; s++) {
                short8 ap = *(const short8*)&Pl[wave][s * 16 + l16][ck * 32 + quad * 8];
                #pragma unroll
                for (int cb = 0; cb < 4; cb++) {
                    O[s][cb] = __builtin_amdgcn_mfma_f32_16x16x32_bf16(ap, bvf[ck][cb], O[s][cb], 0, 0, 0);
                }
            }
        }

        #pragma unroll
        for (int kb = 0; kb < 4; kb++) { kf[kb][0] = kf2[kb][0]; kf[kb][1] = kf2[kb][1]; }
    }

    // deferred row-sum reduction (lanes sharing a row: same quad, l16 0..15)
    #pragma unroll
    for (int s = 0; s < 2; s++)
        #pragma unroll
        for (int r = 0; r < 4; r++)
            #pragma unroll
            for (int off = 1; off < 16; off <<= 1)
                lsum[s][r] += __shfl_xor(lsum[s][r], off);

    // epilogue: out = O/l + q (q from bf16 scaled copy)
    #pragma unroll
    for (int s = 0; s < 2; s++) {
        #pragma unroll
        for (int r = 0; r < 4; r++) {
            float rl = 1.0f / lsum[s][r];
            long nrow = (long)b * Nsz + qbase + s * 16 + quad * 4 + r;
            #pragma unroll
            for (int cb = 0; cb < 4; cb++) {
                int d = cb * 16 + l16;
                float qv = bf2f(qs[nrow * Dsz + d]) * INV_SC;
                out[nrow * Dsz + d] = O[s][cb][r] * rl + qv;
            }
        }
    }
}

extern "C" void kernel_launch(void* const* d_in, const int* in_sizes, int n_in,
                              void* d_out, int out_size, void* d_ws, size_t ws_size,
                              hipStream_t stream) {
    const float* x  = (const float*)d_in[0];
    const float* Wq = (const float*)d_in[1];
    const float* bq = (const float*)d_in[2];
    const float* Wk = (const float*)d_in[3];
    const float* bk = (const float*)d_in[4];
    const float* Wv = (const float*)d_in[5];
    const float* bv = (const float*)d_in[6];
    float* out = (float*)d_out;

    char* ws = (char*)d_ws;
    unsigned short* qsc   = (unsigned short*)ws;                 // 8 MB bf16 q*SC, [n][d]
    unsigned short* ks2   = (unsigned short*)(ws + 0x1000000);   // 8 MB bf16 K frag-major
    unsigned short* vt2   = (unsigned short*)(ws + 0x2000000);   // 8 MB bf16 V^T frag-major
    unsigned short* wfrag = (unsigned short*)(ws + 0x3000000);   // 64 KB W frags

    wprep_kernel<<<dim3(4), dim3(256), 0, stream>>>(Wq, Wk, Wv, wfrag);
    qkv_kernel<<<dim3(1024), dim3(256), 0, stream>>>(
        x, wfrag, bq, bk, bv, qsc, ks2, vt2);
    attn_kernel<<<dim3(512), dim3(256), 0, stream>>>(
        qsc, ks2, vt2, out);
}